// Round 15
// baseline (5741.962 us; speedup 1.0000x reference)
//
#include <hip/hip_runtime.h>

#define B_ 256
#define S_ 512
#define E_ 128
#define H_ 256
#define FH_ 1024
#define HROW 264  // 256 + 8 pad (shorts) -> row offset 132 dwords = 4 mod 32, conflict-free

typedef __bf16 bf16x8 __attribute__((ext_vector_type(8)));
typedef float f32x4 __attribute__((ext_vector_type(4)));
typedef unsigned short u16x4 __attribute__((ext_vector_type(4)));
typedef unsigned short u16x8 __attribute__((ext_vector_type(8)));
typedef unsigned long long u64_;

__device__ __forceinline__ unsigned short f2bf(float f) {
  union { float f; unsigned int u; } a; a.f = f;
  unsigned int u = a.u;
  u += 0x7fffu + ((u >> 16) & 1u);  // RNE
  return (unsigned short)(u >> 16);
}
__device__ __forceinline__ float bf2f(unsigned short v) {
  union { unsigned int u; float f; } a; a.u = ((unsigned int)v) << 16;
  return a.f;
}
// Approximation-rate reciprocal (v_rcp_f32, ~1ulp) -- R14-proven (+21%).
__device__ __forceinline__ float rcp_(float x) {
  float r;
  asm("v_rcp_f32 %0, %1" : "=v"(r) : "v"(x));
  return r;
}
__device__ __forceinline__ float sigm(float x) { return rcp_(1.f + __expf(-x)); }
__device__ __forceinline__ float tanh_(float x) {
  return 1.f - 2.f * rcp_(__expf(2.f * x) + 1.f);
}
// One-instruction packed f32->bf16 (RNE).
__device__ __forceinline__ unsigned int cvt_pk_bf16(float lo, float hi) {
  unsigned int r;
  asm("v_cvt_pk_bf16_f32 %0, %1, %2" : "=v"(r) : "v"(lo), "v"(hi));
  return r;
}

// ---------------- workspace layout (bytes) ----------------
#define OFF_ENC    ((size_t)0)          // enc_out bf16 [256][512][256]  67108864
#define OFF_WHHE   ((size_t)67108864)   // enc_Whh bf16 [1024][256]        524288
#define OFF_WHHP   ((size_t)67633152)   // pb_Whh  bf16                    524288
#define OFF_WREF   ((size_t)68157440)   // Wref    bf16 [256][256]         131072
#define OFF_MENC   ((size_t)68288512)   // M = enc_Wih@W_emb f32 [1024][2]   8192
#define OFF_BIASE  ((size_t)68296704)   // enc_bih+enc_bhh f32 [1024]        4096
#define OFF_XPV    ((size_t)68300800)   // pb x-projection f32 [1024]        4096
#define OFF_FLAGS  ((size_t)68304896)   // u32 flags [16 grp][2 half][8 wave] 1024
#define OFF_HX     ((size_t)68305920)   // h exchange bf16 [2][16][2][128][16] 262144
#define OFF_HFIN   ((size_t)68568064)   // final h f32 [256][256]          262144
#define OFF_QBUF   ((size_t)68830208)   // q f32 [256][256]                262144
#define OFF_UBUF   ((size_t)69092352)   // u f32 [256][512]                524288

// ---------------- K0: prep (weight conversion, folded projections, zeroing) ----
__global__ void k0_prep(const float* __restrict__ eWih, const float* __restrict__ eWhh,
                        const float* __restrict__ ebih, const float* __restrict__ ebhh,
                        const float* __restrict__ pWih, const float* __restrict__ pWhh,
                        const float* __restrict__ pbih, const float* __restrict__ pbhh,
                        const float* __restrict__ W_emb, const float* __restrict__ dec_in,
                        const float* __restrict__ Wref,
                        unsigned short* __restrict__ WhhE, unsigned short* __restrict__ WhhP,
                        unsigned short* __restrict__ Wrefb,
                        float* __restrict__ Menc, float* __restrict__ biasE,
                        float* __restrict__ xpv,
                        unsigned int* __restrict__ flags, float* __restrict__ ubuf) {
  int gid = blockIdx.x * blockDim.x + threadIdx.x;
  int NT = gridDim.x * blockDim.x;
  for (int i = gid; i < FH_ * H_; i += NT) {
    WhhE[i] = f2bf(eWhh[i]);
    WhhP[i] = f2bf(pWhh[i]);
  }
  for (int i = gid; i < H_ * H_; i += NT) Wrefb[i] = f2bf(Wref[i]);
  for (int i = gid; i < B_ * S_; i += NT) ubuf[i] = 0.f;
  if (gid < 256) flags[gid] = 0u;
  if (gid < FH_) {
    int n = gid;
    float m0 = 0.f, m1 = 0.f, xs = 0.f;
    for (int e = 0; e < E_; ++e) {
      float w = eWih[n * E_ + e];
      m0 += w * W_emb[e * 2 + 0];
      m1 += w * W_emb[e * 2 + 1];
      xs += pWih[n * E_ + e] * dec_in[e];
    }
    Menc[n * 2 + 0] = m0;
    Menc[n * 2 + 1] = m1;
    biasE[n] = ebih[n] + ebhh[n];
    xpv[n] = xs + pbih[n] + pbhh[n];
  }
}

// ---------------- K1: persistent dual-LSTM, single-barrier step -------------
// 32 WGs x 512 threads (R14 base = best measured, k1 2.42ms). Pair of WGs
// (halves) split the 1024 gate columns; 32 named weight fragments + asm pin;
// rcp-gates + cvt_pk (R14-proven).
// THIS ROUND: collapse the 3-barrier + tid0-poll skeleton (~45% stall on
// active CUs) to ONE barrier/step:
//  - hbuf DOUBLE-BUFFERED: GEMM reads hbuf[cur], ALL writes go to hbuf[nxt]
//    -> no intra-step LDS hazard; one end-of-step barrier suffices.
//  - PER-WAVE FLAGS (R10-proven): wave w's hx slice is consumed only by peer
//    wave w; each wave drains ITS OWN stores (vmcnt(0)), lane0 sets flag_w,
//    consumer wave polls flag_w directly. No WG rendezvous around the RTT.
//  Slot-parity safety: h(t+2) overwrites hx[par(t)] only after observing
//  peer flag >= t+1, which peer set only after its step t-1 loads drained
//  (vmcnt counts loads) -- monotonic-flag argument, ran correctly in R10.
__launch_bounds__(512)
__attribute__((amdgpu_waves_per_eu(2, 2)))
__global__ void k1_lstm(const float* __restrict__ inp,
                        const unsigned short* __restrict__ WhhE,
                        const unsigned short* __restrict__ WhhP,
                        const float* __restrict__ Menc, const float* __restrict__ biasE,
                        const float* __restrict__ xpv,
                        unsigned short* __restrict__ enc_out,
                        unsigned short* __restrict__ hx,
                        unsigned int* __restrict__ flags,
                        float* __restrict__ hfin) {
  __shared__ unsigned short hbuf[2][16 * HROW];  // h bf16, double-buffered
  __shared__ float xin[2][16][2];
  const int tid = threadIdx.x;
  const int wave = tid >> 6, lane = tid & 63, quad = lane >> 4, l16 = lane & 15;
  const int blk = blockIdx.x;
  const int grp = (blk & 7) | ((blk >> 4) << 3);  // 0..15
  const int half = (blk >> 3) & 1;
  const int kloc = (wave << 4) | l16;    // 0..127 within half
  const int kcol = half * 128 + kloc;    // 0..255 global h-column

  for (int i = tid; i < 16 * HROW; i += 512) hbuf[0][i] = 0;
  if (tid < 32)
    xin[0][tid >> 1][tid & 1] = inp[((grp * 16 + (tid >> 1)) * S_ + 0) * 2 + (tid & 1)];

  float c[4] = {0.f, 0.f, 0.f, 0.f};
  float hreg[4] = {0.f, 0.f, 0.f, 0.f};
  // 32 named weight fragments (4 gates x 8 k-chunks), 128 VGPRs target.
  f32x4 W00, W01, W02, W03, W04, W05, W06, W07;
  f32x4 W10, W11, W12, W13, W14, W15, W16, W17;
  f32x4 W20, W21, W22, W23, W24, W25, W26, W27;
  f32x4 W30, W31, W32, W33, W34, W35, W36, W37;
  float m0c[4], m1c[4], bc[4];
  unsigned int* myflagw = flags + ((grp * 2 + half) << 3) + wave;
  unsigned int* pflagw = flags + ((grp * 2 + (1 - half)) << 3) + wave;
  const f32x4 z4 = {0.f, 0.f, 0.f, 0.f};
  __syncthreads();

  int t = 0;
#pragma unroll 1
  for (int phase = 0; phase < 2; ++phase) {
    const unsigned short* W = phase ? WhhP : WhhE;
#define WLOAD(g)                                                        \
    {                                                                   \
      const unsigned short* wp = W + ((g) * 256 + kcol) * H_ + quad * 8; \
      W##g##0 = *(const f32x4*)(wp + 0 * 32);                           \
      W##g##1 = *(const f32x4*)(wp + 1 * 32);                           \
      W##g##2 = *(const f32x4*)(wp + 2 * 32);                           \
      W##g##3 = *(const f32x4*)(wp + 3 * 32);                           \
      W##g##4 = *(const f32x4*)(wp + 4 * 32);                           \
      W##g##5 = *(const f32x4*)(wp + 5 * 32);                           \
      W##g##6 = *(const f32x4*)(wp + 6 * 32);                           \
      W##g##7 = *(const f32x4*)(wp + 7 * 32);                           \
    }
    WLOAD(0) WLOAD(1) WLOAD(2) WLOAD(3)
#undef WLOAD
    asm volatile(""
                 : "+v"(W00), "+v"(W01), "+v"(W02), "+v"(W03),
                   "+v"(W04), "+v"(W05), "+v"(W06), "+v"(W07),
                   "+v"(W10), "+v"(W11), "+v"(W12), "+v"(W13),
                   "+v"(W14), "+v"(W15), "+v"(W16), "+v"(W17),
                   "+v"(W20), "+v"(W21), "+v"(W22), "+v"(W23),
                   "+v"(W24), "+v"(W25), "+v"(W26), "+v"(W27),
                   "+v"(W30), "+v"(W31), "+v"(W32), "+v"(W33),
                   "+v"(W34), "+v"(W35), "+v"(W36), "+v"(W37));
#pragma unroll
    for (int gg = 0; gg < 4; ++gg) {
      int n = gg * 256 + kcol;
      if (phase == 0) {
        m0c[gg] = Menc[n * 2 + 0]; m1c[gg] = Menc[n * 2 + 1]; bc[gg] = biasE[n];
      } else {
        m0c[gg] = 0.f; m1c[gg] = 0.f; bc[gg] = xpv[n];
      }
    }
#pragma unroll 1
    for (int step = 0; step < 512; ++step, ++t) {
      const int cur = t & 1, nxt = cur ^ 1;
      // ---- prefetch next step's x (latency hidden under GEMM) ----
      float xpre = 0.f;
      if (phase == 0 && tid < 32) {
        int sN = (step < 511) ? step + 1 : 511;
        xpre = inp[((grp * 16 + (tid >> 1)) * S_ + sN) * 2 + (tid & 1)];
      }
      // ---- GEMM: g = h @ Whh^T (this WG's 512 columns) ----
      f32x4 acc0 = z4, acc1 = z4, acc2 = z4, acc3 = z4;
#define MSTEP(kt)                                                                  \
      {                                                                            \
        bf16x8 Af = *(const bf16x8*)(&hbuf[cur][0] + l16 * HROW + kt * 32 + quad * 8); \
        acc0 = __builtin_amdgcn_mfma_f32_16x16x32_bf16(                            \
            Af, __builtin_bit_cast(bf16x8, W0##kt), acc0, 0, 0, 0);                \
        acc1 = __builtin_amdgcn_mfma_f32_16x16x32_bf16(                            \
            Af, __builtin_bit_cast(bf16x8, W1##kt), acc1, 0, 0, 0);                \
        acc2 = __builtin_amdgcn_mfma_f32_16x16x32_bf16(                            \
            Af, __builtin_bit_cast(bf16x8, W2##kt), acc2, 0, 0, 0);                \
        acc3 = __builtin_amdgcn_mfma_f32_16x16x32_bf16(                            \
            Af, __builtin_bit_cast(bf16x8, W3##kt), acc3, 0, 0, 0);                \
      }
      MSTEP(0) MSTEP(1) MSTEP(2) MSTEP(3) MSTEP(4) MSTEP(5) MSTEP(6) MSTEP(7)
#undef MSTEP
      // ---- gates (approximation-rate math) ----
      float hv[4];
#pragma unroll
      for (int r = 0; r < 4; ++r) {
        int bl = quad * 4 + r;
        float x0 = xin[cur][bl][0], x1 = xin[cur][bl][1];
        float gi = acc0[r] + x0 * m0c[0] + x1 * m1c[0] + bc[0];
        float gf = acc1[r] + x0 * m0c[1] + x1 * m1c[1] + bc[1];
        float gc = acc2[r] + x0 * m0c[2] + x1 * m1c[2] + bc[2];
        float go = acc3[r] + x0 * m0c[3] + x1 * m1c[3] + bc[3];
        float cn = sigm(gf) * c[r] + sigm(gi) * tanh_(gc);
        c[r] = cn;
        hv[r] = sigm(go) * tanh_(cn);
        hreg[r] = hv[r];
      }
      unsigned int pkA = cvt_pk_bf16(hv[0], hv[1]);
      unsigned int pkB = cvt_pk_bf16(hv[2], hv[3]);
      unsigned short hb[4];
      hb[0] = (unsigned short)pkA; hb[1] = (unsigned short)(pkA >> 16);
      hb[2] = (unsigned short)pkB; hb[3] = (unsigned short)(pkB >> 16);
      // ---- publish: enc_out + hx (slot = parity of t+1) ----
      if (phase == 0) {
#pragma unroll
        for (int r = 0; r < 4; ++r)
          enc_out[(((size_t)(grp * 16 + quad * 4 + r) * S_ + step)) * H_ + kcol] = hb[r];
      }
      {
        unsigned short* hxs = hx + ((size_t)(nxt * 32 + grp * 2 + half)) * 2048;
        u64_ pack = (u64_)pkA | ((u64_)pkB << 32);
        __hip_atomic_store((u64_*)(hxs + kloc * 16 + quad * 4), pack,
                           __ATOMIC_RELAXED, __HIP_MEMORY_SCOPE_AGENT);
      }
      // ---- own half into hbuf[nxt]; xin[nxt] ----
#pragma unroll
      for (int r = 0; r < 4; ++r) hbuf[nxt][(quad * 4 + r) * HROW + kcol] = hb[r];
      if (phase == 0 && tid < 32) xin[nxt][tid >> 1][tid & 1] = xpre;
      // ---- per-wave drain + flag; poll matching peer wave; import ----
      asm volatile("s_waitcnt vmcnt(0)" ::: "memory");
      if (lane == 0)
        __hip_atomic_store(myflagw, (unsigned int)(t + 1), __ATOMIC_RELAXED,
                           __HIP_MEMORY_SCOPE_AGENT);
      {
        const unsigned int target = (unsigned int)(t + 1);
        while (__hip_atomic_load(pflagw, __ATOMIC_RELAXED, __HIP_MEMORY_SCOPE_AGENT) <
               target) {
          __builtin_amdgcn_s_sleep(1);
        }
        const unsigned short* ph =
            hx + ((size_t)(nxt * 32 + grp * 2 + (1 - half))) * 2048;
        u64_ pv = __hip_atomic_load((const u64_*)(ph + tid * 4), __ATOMIC_RELAXED,
                                    __HIP_MEMORY_SCOPE_AGENT);
        int kp = tid >> 2, r0 = (tid & 3) * 4;
        unsigned short* dst = &hbuf[nxt][0] + (1 - half) * 128 + kp;
        dst[(size_t)(r0 + 0) * HROW] = (unsigned short)(pv);
        dst[(size_t)(r0 + 1) * HROW] = (unsigned short)(pv >> 16);
        dst[(size_t)(r0 + 2) * HROW] = (unsigned short)(pv >> 32);
        dst[(size_t)(r0 + 3) * HROW] = (unsigned short)(pv >> 48);
      }
      __syncthreads();  // ONE barrier: hbuf[nxt]/xin[nxt] complete, step fence
    }
  }
  // final h (fp32) for the attention query
#pragma unroll
  for (int r = 0; r < 4; ++r)
    hfin[(grp * 16 + quad * 4 + r) * H_ + kcol] = hreg[r];
}

// ---------------- K1b: q = h @ Wq^T + bq (fp32) ----------------
__global__ void k1b_q(const float* __restrict__ hfin, const float* __restrict__ Wq,
                      const float* __restrict__ bq, float* __restrict__ qbuf) {
  __shared__ float hl[H_];
  int b = blockIdx.x, j = threadIdx.x;
  hl[j] = hfin[b * H_ + j];
  __syncthreads();
  float s = bq[j];
  const float* w = Wq + j * H_;
  for (int k = 0; k < H_; ++k) s += hl[k] * w[k];
  qbuf[b * H_ + j] = s;
}

// ---------------- K2: u = tanh(enc_out@Wref^T + bref + q) @ V (fused) ----------
__launch_bounds__(512)
__global__ void k2_att(const unsigned short* __restrict__ enc_out,
                       const unsigned short* __restrict__ Wrefb,
                       const float* __restrict__ qbuf, const float* __restrict__ bref,
                       const float* __restrict__ V, float* __restrict__ ubuf) {
  __shared__ unsigned short Bs[128 * HROW];
  __shared__ float qs[128], Vs[128];
  int tid = threadIdx.x;
  int wave = tid >> 6, lane = tid & 63, quad = lane >> 4, l16 = lane & 15;
  int rowblk = blockIdx.x >> 1, nb = blockIdx.x & 1;
  int b = rowblk >> 2;
  {  // stage Wref block [nb*128 .. +128) x 256 into LDS
    int nl = tid >> 2, seg = tid & 3;
    const unsigned short* src = Wrefb + (nb * 128 + nl) * H_ + seg * 64;
    unsigned short* dst = Bs + nl * HROW + seg * 64;
#pragma unroll
    for (int i = 0; i < 8; ++i) *(u16x8*)(dst + i * 8) = *(const u16x8*)(src + i * 8);
  }
  if (tid < 128) {
    int j = nb * 128 + tid;
    qs[tid] = qbuf[b * H_ + j] + bref[j];
    Vs[tid] = V[j];
  }
  __syncthreads();
  int rw = rowblk * 128 + wave * 16 + l16;  // global (b,s) row
  const f32x4 z4 = {0.f, 0.f, 0.f, 0.f};
  f32x4 acc[8];
#pragma unroll
  for (int kt = 0; kt < 8; ++kt) {
    bf16x8 af = *(const bf16x8*)(enc_out + (size_t)rw * H_ + kt * 32 + quad * 8);
#pragma unroll
    for (int nt = 0; nt < 8; ++nt) {
      bf16x8 bfr = *(const bf16x8*)(Bs + (nt * 16 + l16) * HROW + kt * 32 + quad * 8);
      acc[nt] = __builtin_amdgcn_mfma_f32_16x16x32_bf16(af, bfr, (kt == 0) ? z4 : acc[nt],
                                                        0, 0, 0);
    }
  }
  float part[4] = {0.f, 0.f, 0.f, 0.f};
#pragma unroll
  for (int nt = 0; nt < 8; ++nt) {
    float qv = qs[nt * 16 + l16], vv = Vs[nt * 16 + l16];
#pragma unroll
    for (int r = 0; r < 4; ++r) part[r] += tanh_(acc[nt][r] + qv) * vv;
  }
#pragma unroll
  for (int m = 1; m < 16; m <<= 1) {
#pragma unroll
    for (int r = 0; r < 4; ++r) part[r] += __shfl_xor(part[r], m, 64);
  }
  if (l16 == 0) {
    int s0 = (rowblk & 3) * 128 + wave * 16 + quad * 4;
#pragma unroll
    for (int r = 0; r < 4; ++r) atomicAdd(&ubuf[b * S_ + s0 + r], part[r]);
  }
}

// ---------------- K3: softmax + glimpse + decoder head ----------------
__global__ void k3_head(const float* __restrict__ ubuf,
                        const unsigned short* __restrict__ enc_out,
                        const float* __restrict__ Wd1, const float* __restrict__ Wd2,
                        float* __restrict__ out) {
  __shared__ float sm[512];
  __shared__ float red[256];
  __shared__ float gl[256];
  int b = blockIdx.x, tid = threadIdx.x;
  float u0 = ubuf[b * S_ + tid], u1 = ubuf[b * S_ + 256 + tid];
  red[tid] = fmaxf(u0, u1);
  __syncthreads();
  for (int s = 128; s > 0; s >>= 1) {
    if (tid < s) red[tid] = fmaxf(red[tid], red[tid + s]);
    __syncthreads();
  }
  float mx = red[0];
  __syncthreads();
  float e0 = __expf(u0 - mx), e1 = __expf(u1 - mx);
  red[tid] = e0 + e1;
  __syncthreads();
  for (int s = 128; s > 0; s >>= 1) {
    if (tid < s) red[tid] += red[tid + s];
    __syncthreads();
  }
  float inv = 1.f / red[0];
  sm[tid] = e0 * inv;
  sm[256 + tid] = e1 * inv;
  __syncthreads();
  float g = 0.f;
  const unsigned short* eo = enc_out + (size_t)b * S_ * H_ + tid;
  for (int s = 0; s < S_; ++s) g += sm[s] * bf2f(eo[(size_t)s * H_]);
  gl[tid] = g;
  __syncthreads();
  float y = 0.f;
  const float* w = Wd1 + tid * H_;
  for (int j = 0; j < H_; ++j) y += w[j] * gl[j];
  y = fmaxf(y, 0.f) * Wd2[tid];
  red[tid] = y;
  __syncthreads();
  for (int s = 128; s > 0; s >>= 1) {
    if (tid < s) red[tid] += red[tid + s];
    __syncthreads();
  }
  if (tid == 0) out[b] = red[0];
}

extern "C" void kernel_launch(void* const* d_in, const int* in_sizes, int n_in,
                              void* d_out, int out_size, void* d_ws, size_t ws_size,
                              hipStream_t stream) {
  (void)in_sizes; (void)n_in; (void)out_size; (void)ws_size;
  const float* inp    = (const float*)d_in[0];
  const float* W_emb  = (const float*)d_in[1];
  const float* dec_in = (const float*)d_in[2];
  const float* eWih   = (const float*)d_in[3];
  const float* eWhh   = (const float*)d_in[4];
  const float* ebih   = (const float*)d_in[5];
  const float* ebhh   = (const float*)d_in[6];
  const float* pWih   = (const float*)d_in[7];
  const float* pWhh   = (const float*)d_in[8];
  const float* pbih   = (const float*)d_in[9];
  const float* pbhh   = (const float*)d_in[10];
  const float* Wq     = (const float*)d_in[11];
  const float* bq     = (const float*)d_in[12];
  const float* Wref   = (const float*)d_in[13];
  const float* bref   = (const float*)d_in[14];
  const float* V      = (const float*)d_in[15];
  const float* Wd1    = (const float*)d_in[16];
  const float* Wd2    = (const float*)d_in[17];
  float* out = (float*)d_out;

  char* ws = (char*)d_ws;
  unsigned short* enc_out = (unsigned short*)(ws + OFF_ENC);
  unsigned short* WhhE    = (unsigned short*)(ws + OFF_WHHE);
  unsigned short* WhhP    = (unsigned short*)(ws + OFF_WHHP);
  unsigned short* Wrefb   = (unsigned short*)(ws + OFF_WREF);
  float* Menc  = (float*)(ws + OFF_MENC);
  float* biasE = (float*)(ws + OFF_BIASE);
  float* xpv   = (float*)(ws + OFF_XPV);
  unsigned int* flags = (unsigned int*)(ws + OFF_FLAGS);
  unsigned short* hx  = (unsigned short*)(ws + OFF_HX);
  float* hfin = (float*)(ws + OFF_HFIN);
  float* qbuf = (float*)(ws + OFF_QBUF);
  float* ubuf = (float*)(ws + OFF_UBUF);

  hipLaunchKernelGGL(k0_prep, dim3(256), dim3(256), 0, stream,
                     eWih, eWhh, ebih, ebhh, pWih, pWhh, pbih, pbhh, W_emb, dec_in,
                     Wref, WhhE, WhhP, Wrefb, Menc, biasE, xpv, flags, ubuf);
  hipLaunchKernelGGL(k1_lstm, dim3(32), dim3(512), 0, stream,
                     inp, WhhE, WhhP, Menc, biasE, xpv, enc_out, hx, flags, hfin);
  hipLaunchKernelGGL(k1b_q, dim3(256), dim3(256), 0, stream, hfin, Wq, bq, qbuf);
  hipLaunchKernelGGL(k2_att, dim3(2048), dim3(512), 0, stream,
                     enc_out, Wrefb, qbuf, bref, V, ubuf);
  hipLaunchKernelGGL(k3_head, dim3(256), dim3(256), 0, stream,
                     ubuf, enc_out, Wd1, Wd2, out);
}

// Round 16
// 2593.664 us; speedup vs baseline: 2.2138x; 2.2138x over previous
//
#include <hip/hip_runtime.h>

#define B_ 256
#define S_ 512
#define E_ 128
#define H_ 256
#define FH_ 1024
#define HROW 264  // 256 + 8 pad (shorts) -> row offset 132 dwords = 4 mod 32, conflict-free

typedef __bf16 bf16x8 __attribute__((ext_vector_type(8)));
typedef float f32x4 __attribute__((ext_vector_type(4)));
typedef unsigned short u16x4 __attribute__((ext_vector_type(4)));
typedef unsigned short u16x8 __attribute__((ext_vector_type(8)));
typedef unsigned long long u64_;

__device__ __forceinline__ unsigned short f2bf(float f) {
  union { float f; unsigned int u; } a; a.f = f;
  unsigned int u = a.u;
  u += 0x7fffu + ((u >> 16) & 1u);  // RNE
  return (unsigned short)(u >> 16);
}
__device__ __forceinline__ float bf2f(unsigned short v) {
  union { unsigned int u; float f; } a; a.u = ((unsigned int)v) << 16;
  return a.f;
}
// Approximation-rate reciprocal (v_rcp_f32, ~1ulp) -- R14-proven (+21%).
__device__ __forceinline__ float rcp_(float x) {
  float r;
  asm("v_rcp_f32 %0, %1" : "=v"(r) : "v"(x));
  return r;
}
__device__ __forceinline__ float sigm(float x) { return rcp_(1.f + __expf(-x)); }
__device__ __forceinline__ float tanh_(float x) {
  return 1.f - 2.f * rcp_(__expf(2.f * x) + 1.f);
}
// One-instruction packed f32->bf16 (RNE).
__device__ __forceinline__ unsigned int cvt_pk_bf16(float lo, float hi) {
  unsigned int r;
  asm("v_cvt_pk_bf16_f32 %0, %1, %2" : "=v"(r) : "v"(lo), "v"(hi));
  return r;
}

// ---------------- workspace layout (bytes) ----------------
#define OFF_ENC    ((size_t)0)          // enc_out bf16 [256][512][256]  67108864
#define OFF_WHHE   ((size_t)67108864)   // enc_Whh bf16 [1024][256]        524288
#define OFF_WHHP   ((size_t)67633152)   // pb_Whh  bf16                    524288
#define OFF_WREF   ((size_t)68157440)   // Wref    bf16 [256][256]         131072
#define OFF_MENC   ((size_t)68288512)   // M = enc_Wih@W_emb f32 [1024][2]   8192
#define OFF_BIASE  ((size_t)68296704)   // enc_bih+enc_bhh f32 [1024]        4096
#define OFF_XPV    ((size_t)68300800)   // pb x-projection f32 [1024]        4096
#define OFF_FLAGS  ((size_t)68304896)   // u32 flags                         1024
#define OFF_HX     ((size_t)68305920)   // h exchange bf16 [2][16][2][128][16] 262144
#define OFF_HFIN   ((size_t)68568064)   // final h f32 [256][256]          262144
#define OFF_QBUF   ((size_t)68830208)   // q f32 [256][256]                262144
#define OFF_UBUF   ((size_t)69092352)   // u f32 [256][512]                524288

// ---------------- K0: prep (weight conversion, folded projections, zeroing) ----
__global__ void k0_prep(const float* __restrict__ eWih, const float* __restrict__ eWhh,
                        const float* __restrict__ ebih, const float* __restrict__ ebhh,
                        const float* __restrict__ pWih, const float* __restrict__ pWhh,
                        const float* __restrict__ pbih, const float* __restrict__ pbhh,
                        const float* __restrict__ W_emb, const float* __restrict__ dec_in,
                        const float* __restrict__ Wref,
                        unsigned short* __restrict__ WhhE, unsigned short* __restrict__ WhhP,
                        unsigned short* __restrict__ Wrefb,
                        float* __restrict__ Menc, float* __restrict__ biasE,
                        float* __restrict__ xpv,
                        unsigned int* __restrict__ flags, float* __restrict__ ubuf) {
  int gid = blockIdx.x * blockDim.x + threadIdx.x;
  int NT = gridDim.x * blockDim.x;
  for (int i = gid; i < FH_ * H_; i += NT) {
    WhhE[i] = f2bf(eWhh[i]);
    WhhP[i] = f2bf(pWhh[i]);
  }
  for (int i = gid; i < H_ * H_; i += NT) Wrefb[i] = f2bf(Wref[i]);
  for (int i = gid; i < B_ * S_; i += NT) ubuf[i] = 0.f;
  if (gid < 256) flags[gid] = 0u;
  if (gid < FH_) {
    int n = gid;
    float m0 = 0.f, m1 = 0.f, xs = 0.f;
    for (int e = 0; e < E_; ++e) {
      float w = eWih[n * E_ + e];
      m0 += w * W_emb[e * 2 + 0];
      m1 += w * W_emb[e * 2 + 1];
      xs += pWih[n * E_ + e] * dec_in[e];
    }
    Menc[n * 2 + 0] = m0;
    Menc[n * 2 + 1] = m1;
    biasE[n] = ebih[n] + ebhh[n];
    xpv[n] = xs + pbih[n] + pbhh[n];
  }
}

// ---------------- K1: persistent dual-LSTM recurrence (R14 skeleton) --------
// 32 WGs x 512 threads; pair of WGs (halves) split the 1024 gate columns;
// 32 named weight fragments + asm pin; rcp-gates + cvt_pk (R14-proven,
// best measured k1 2.42ms). Skeleton: 3 barriers + tid0-centralized flag RTT
// (R15 proved decentralized per-wave polling regresses 2.4x).
// THIS ROUND (R13 showed step cost scales with per-wave VMEM work):
//  - enc_out: DELAYED COALESCED store. At iteration t, hbuf still holds h(t)
//    (= enc_out row t-1) until the post-bar(b) update; read it as u16x4 and
//    store ONE 8B coalesced store/thread instead of 4 scattered 2B stores.
//  - hx store issued first after cvt_pk (latency-critical payload).
//  - own-half hbuf writes moved between bar(a) and bar(b): overlap tid0's RTT.
__launch_bounds__(512)
__attribute__((amdgpu_waves_per_eu(2, 2)))
__global__ void k1_lstm(const float* __restrict__ inp,
                        const unsigned short* __restrict__ WhhE,
                        const unsigned short* __restrict__ WhhP,
                        const float* __restrict__ Menc, const float* __restrict__ biasE,
                        const float* __restrict__ xpv,
                        unsigned short* __restrict__ enc_out,
                        unsigned short* __restrict__ hx,
                        unsigned int* __restrict__ flags,
                        float* __restrict__ hfin) {
  __shared__ unsigned short hbuf[16 * HROW];  // h bf16, 16 rows x (256+pad)
  __shared__ float xin[16][2];
  const int tid = threadIdx.x;
  const int wave = tid >> 6, lane = tid & 63, quad = lane >> 4, l16 = lane & 15;
  const int blk = blockIdx.x;
  const int grp = (blk & 7) | ((blk >> 4) << 3);  // 0..15
  const int half = (blk >> 3) & 1;
  const int kloc = (wave << 4) | l16;    // 0..127 within half
  const int kcol = half * 128 + kloc;    // 0..255 global h-column
  // delayed enc-store geometry: 16 rows x 128 cols = 2048 shorts / 512 thr
  const int erow = tid >> 5;             // 0..15 batch row within group
  const int ecol = (tid & 31) * 4;       // 0..124 column within half

  for (int i = tid; i < 16 * HROW; i += 512) hbuf[i] = 0;
  if (tid < 32) xin[tid >> 1][tid & 1] = inp[((grp * 16 + (tid >> 1)) * S_ + 0) * 2 + (tid & 1)];

  float c[4] = {0.f, 0.f, 0.f, 0.f};
  float hreg[4] = {0.f, 0.f, 0.f, 0.f};
  // 32 named weight fragments (4 gates x 8 k-chunks), 128 VGPRs target.
  f32x4 W00, W01, W02, W03, W04, W05, W06, W07;
  f32x4 W10, W11, W12, W13, W14, W15, W16, W17;
  f32x4 W20, W21, W22, W23, W24, W25, W26, W27;
  f32x4 W30, W31, W32, W33, W34, W35, W36, W37;
  float m0c[4], m1c[4], bc[4];
  unsigned int* myflag = flags + grp * 2 + half;
  unsigned int* pflag = flags + grp * 2 + (1 - half);
  const f32x4 z4 = {0.f, 0.f, 0.f, 0.f};
  __syncthreads();

  int t = 0;
#pragma unroll 1
  for (int phase = 0; phase < 2; ++phase) {
    const unsigned short* W = phase ? WhhP : WhhE;
#define WLOAD(g)                                                        \
    {                                                                   \
      const unsigned short* wp = W + ((g) * 256 + kcol) * H_ + quad * 8; \
      W##g##0 = *(const f32x4*)(wp + 0 * 32);                           \
      W##g##1 = *(const f32x4*)(wp + 1 * 32);                           \
      W##g##2 = *(const f32x4*)(wp + 2 * 32);                           \
      W##g##3 = *(const f32x4*)(wp + 3 * 32);                           \
      W##g##4 = *(const f32x4*)(wp + 4 * 32);                           \
      W##g##5 = *(const f32x4*)(wp + 5 * 32);                           \
      W##g##6 = *(const f32x4*)(wp + 6 * 32);                           \
      W##g##7 = *(const f32x4*)(wp + 7 * 32);                           \
    }
    WLOAD(0) WLOAD(1) WLOAD(2) WLOAD(3)
#undef WLOAD
    asm volatile(""
                 : "+v"(W00), "+v"(W01), "+v"(W02), "+v"(W03),
                   "+v"(W04), "+v"(W05), "+v"(W06), "+v"(W07),
                   "+v"(W10), "+v"(W11), "+v"(W12), "+v"(W13),
                   "+v"(W14), "+v"(W15), "+v"(W16), "+v"(W17),
                   "+v"(W20), "+v"(W21), "+v"(W22), "+v"(W23),
                   "+v"(W24), "+v"(W25), "+v"(W26), "+v"(W27),
                   "+v"(W30), "+v"(W31), "+v"(W32), "+v"(W33),
                   "+v"(W34), "+v"(W35), "+v"(W36), "+v"(W37));
#pragma unroll
    for (int gg = 0; gg < 4; ++gg) {
      int n = gg * 256 + kcol;
      if (phase == 0) {
        m0c[gg] = Menc[n * 2 + 0]; m1c[gg] = Menc[n * 2 + 1]; bc[gg] = biasE[n];
      } else {
        m0c[gg] = 0.f; m1c[gg] = 0.f; bc[gg] = xpv[n];
      }
    }
#pragma unroll 1
    for (int step = 0; step < 512; ++step, ++t) {
      // ---- prefetch next step's x (latency hidden under GEMM) ----
      float xpre = 0.f;
      if (phase == 0 && tid < 32) {
        int sN = (step < 511) ? step + 1 : 511;
        xpre = inp[((grp * 16 + (tid >> 1)) * S_ + sN) * 2 + (tid & 1)];
      }
      // ---- GEMM: g = h @ Whh^T (this WG's 512 columns) ----
      f32x4 acc0 = z4, acc1 = z4, acc2 = z4, acc3 = z4;
#define MSTEP(kt)                                                              \
      {                                                                        \
        bf16x8 Af = *(const bf16x8*)(hbuf + l16 * HROW + kt * 32 + quad * 8);  \
        acc0 = __builtin_amdgcn_mfma_f32_16x16x32_bf16(                        \
            Af, __builtin_bit_cast(bf16x8, W0##kt), acc0, 0, 0, 0);            \
        acc1 = __builtin_amdgcn_mfma_f32_16x16x32_bf16(                        \
            Af, __builtin_bit_cast(bf16x8, W1##kt), acc1, 0, 0, 0);            \
        acc2 = __builtin_amdgcn_mfma_f32_16x16x32_bf16(                        \
            Af, __builtin_bit_cast(bf16x8, W2##kt), acc2, 0, 0, 0);            \
        acc3 = __builtin_amdgcn_mfma_f32_16x16x32_bf16(                        \
            Af, __builtin_bit_cast(bf16x8, W3##kt), acc3, 0, 0, 0);            \
      }
      MSTEP(0) MSTEP(1) MSTEP(2) MSTEP(3) MSTEP(4) MSTEP(5) MSTEP(6) MSTEP(7)
#undef MSTEP
      // ---- delayed coalesced enc_out store: row t-1 from hbuf (stable until
      //      the post-bar(b) update). t in [1,512] covers rows 0..511. ----
      if (t >= 1 && t <= 512) {
        u16x4 v = *(const u16x4*)(hbuf + erow * HROW + half * 128 + ecol);
        *(u16x4*)(enc_out + (((size_t)(grp * 16 + erow) * S_ + (t - 1))) * H_ +
                  half * 128 + ecol) = v;
      }
      // ---- gates (approximation-rate math) ----
      float hv[4];
#pragma unroll
      for (int r = 0; r < 4; ++r) {
        int bl = quad * 4 + r;
        float x0 = xin[bl][0], x1 = xin[bl][1];
        float gi = acc0[r] + x0 * m0c[0] + x1 * m1c[0] + bc[0];
        float gf = acc1[r] + x0 * m0c[1] + x1 * m1c[1] + bc[1];
        float gc = acc2[r] + x0 * m0c[2] + x1 * m1c[2] + bc[2];
        float go = acc3[r] + x0 * m0c[3] + x1 * m1c[3] + bc[3];
        float cn = sigm(gf) * c[r] + sigm(gi) * tanh_(gc);
        c[r] = cn;
        hv[r] = sigm(go) * tanh_(cn);
        hreg[r] = hv[r];
      }
      unsigned int pkA = cvt_pk_bf16(hv[0], hv[1]);
      unsigned int pkB = cvt_pk_bf16(hv[2], hv[3]);
      unsigned short hb[4];
      hb[0] = (unsigned short)pkA; hb[1] = (unsigned short)(pkA >> 16);
      hb[2] = (unsigned short)pkB; hb[3] = (unsigned short)(pkB >> 16);
      // ---- publish hx FIRST (latency-critical) ----
      {
        unsigned short* hxs = hx + ((size_t)((t & 1) * 32 + grp * 2 + half)) * 2048;
        u64_ pack = (u64_)pkA | ((u64_)pkB << 32);
        __hip_atomic_store((u64_*)(hxs + kloc * 16 + quad * 4), pack,
                           __ATOMIC_RELAXED, __HIP_MEMORY_SCOPE_AGENT);
      }
      __syncthreads();  // (a) all hbuf reads done; hx+enc stores drained (vmcnt0)
      // ---- own-half hbuf update + xin overlap tid0's flag RTT ----
#pragma unroll
      for (int r = 0; r < 4; ++r) hbuf[(quad * 4 + r) * HROW + kcol] = hb[r];
      if (phase == 0 && tid < 32) xin[tid >> 1][tid & 1] = xpre;
      if (tid == 0) {
        __hip_atomic_store(myflag, (unsigned int)(t + 1), __ATOMIC_RELAXED,
                           __HIP_MEMORY_SCOPE_AGENT);
        while (__hip_atomic_load(pflag, __ATOMIC_RELAXED, __HIP_MEMORY_SCOPE_AGENT) <
               (unsigned int)(t + 1)) {
          __builtin_amdgcn_s_sleep(1);
        }
      }
      __syncthreads();  // (b)
      // ---- import peer half from hx ----
      {
        const unsigned short* ph = hx + ((size_t)((t & 1) * 32 + grp * 2 + (1 - half))) * 2048;
        u64_ pv = __hip_atomic_load((const u64_*)(ph + tid * 4), __ATOMIC_RELAXED,
                                    __HIP_MEMORY_SCOPE_AGENT);
        int kp = tid >> 2, r0 = (tid & 3) * 4;
        unsigned short* dst = hbuf + (1 - half) * 128 + kp;
        dst[(size_t)(r0 + 0) * HROW] = (unsigned short)(pv);
        dst[(size_t)(r0 + 1) * HROW] = (unsigned short)(pv >> 16);
        dst[(size_t)(r0 + 2) * HROW] = (unsigned short)(pv >> 32);
        dst[(size_t)(r0 + 3) * HROW] = (unsigned short)(pv >> 48);
      }
      __syncthreads();  // (c) h ready for next step
    }
  }
  // final h (fp32) for the attention query
#pragma unroll
  for (int r = 0; r < 4; ++r)
    hfin[(grp * 16 + quad * 4 + r) * H_ + kcol] = hreg[r];
}

// ---------------- K1b: q = h @ Wq^T + bq (fp32) ----------------
__global__ void k1b_q(const float* __restrict__ hfin, const float* __restrict__ Wq,
                      const float* __restrict__ bq, float* __restrict__ qbuf) {
  __shared__ float hl[H_];
  int b = blockIdx.x, j = threadIdx.x;
  hl[j] = hfin[b * H_ + j];
  __syncthreads();
  float s = bq[j];
  const float* w = Wq + j * H_;
  for (int k = 0; k < H_; ++k) s += hl[k] * w[k];
  qbuf[b * H_ + j] = s;
}

// ---------------- K2: u = tanh(enc_out@Wref^T + bref + q) @ V (fused) ----------
__launch_bounds__(512)
__global__ void k2_att(const unsigned short* __restrict__ enc_out,
                       const unsigned short* __restrict__ Wrefb,
                       const float* __restrict__ qbuf, const float* __restrict__ bref,
                       const float* __restrict__ V, float* __restrict__ ubuf) {
  __shared__ unsigned short Bs[128 * HROW];
  __shared__ float qs[128], Vs[128];
  int tid = threadIdx.x;
  int wave = tid >> 6, lane = tid & 63, quad = lane >> 4, l16 = lane & 15;
  int rowblk = blockIdx.x >> 1, nb = blockIdx.x & 1;
  int b = rowblk >> 2;
  {  // stage Wref block [nb*128 .. +128) x 256 into LDS
    int nl = tid >> 2, seg = tid & 3;
    const unsigned short* src = Wrefb + (nb * 128 + nl) * H_ + seg * 64;
    unsigned short* dst = Bs + nl * HROW + seg * 64;
#pragma unroll
    for (int i = 0; i < 8; ++i) *(u16x8*)(dst + i * 8) = *(const u16x8*)(src + i * 8);
  }
  if (tid < 128) {
    int j = nb * 128 + tid;
    qs[tid] = qbuf[b * H_ + j] + bref[j];
    Vs[tid] = V[j];
  }
  __syncthreads();
  int rw = rowblk * 128 + wave * 16 + l16;  // global (b,s) row
  const f32x4 z4 = {0.f, 0.f, 0.f, 0.f};
  f32x4 acc[8];
#pragma unroll
  for (int kt = 0; kt < 8; ++kt) {
    bf16x8 af = *(const bf16x8*)(enc_out + (size_t)rw * H_ + kt * 32 + quad * 8);
#pragma unroll
    for (int nt = 0; nt < 8; ++nt) {
      bf16x8 bfr = *(const bf16x8*)(Bs + (nt * 16 + l16) * HROW + kt * 32 + quad * 8);
      acc[nt] = __builtin_amdgcn_mfma_f32_16x16x32_bf16(af, bfr, (kt == 0) ? z4 : acc[nt],
                                                        0, 0, 0);
    }
  }
  float part[4] = {0.f, 0.f, 0.f, 0.f};
#pragma unroll
  for (int nt = 0; nt < 8; ++nt) {
    float qv = qs[nt * 16 + l16], vv = Vs[nt * 16 + l16];
#pragma unroll
    for (int r = 0; r < 4; ++r) part[r] += tanh_(acc[nt][r] + qv) * vv;
  }
#pragma unroll
  for (int m = 1; m < 16; m <<= 1) {
#pragma unroll
    for (int r = 0; r < 4; ++r) part[r] += __shfl_xor(part[r], m, 64);
  }
  if (l16 == 0) {
    int s0 = (rowblk & 3) * 128 + wave * 16 + quad * 4;
#pragma unroll
    for (int r = 0; r < 4; ++r) atomicAdd(&ubuf[b * S_ + s0 + r], part[r]);
  }
}

// ---------------- K3: softmax + glimpse + decoder head ----------------
__global__ void k3_head(const float* __restrict__ ubuf,
                        const unsigned short* __restrict__ enc_out,
                        const float* __restrict__ Wd1, const float* __restrict__ Wd2,
                        float* __restrict__ out) {
  __shared__ float sm[512];
  __shared__ float red[256];
  __shared__ float gl[256];
  int b = blockIdx.x, tid = threadIdx.x;
  float u0 = ubuf[b * S_ + tid], u1 = ubuf[b * S_ + 256 + tid];
  red[tid] = fmaxf(u0, u1);
  __syncthreads();
  for (int s = 128; s > 0; s >>= 1) {
    if (tid < s) red[tid] = fmaxf(red[tid], red[tid + s]);
    __syncthreads();
  }
  float mx = red[0];
  __syncthreads();
  float e0 = __expf(u0 - mx), e1 = __expf(u1 - mx);
  red[tid] = e0 + e1;
  __syncthreads();
  for (int s = 128; s > 0; s >>= 1) {
    if (tid < s) red[tid] += red[tid + s];
    __syncthreads();
  }
  float inv = 1.f / red[0];
  sm[tid] = e0 * inv;
  sm[256 + tid] = e1 * inv;
  __syncthreads();
  float g = 0.f;
  const unsigned short* eo = enc_out + (size_t)b * S_ * H_ + tid;
  for (int s = 0; s < S_; ++s) g += sm[s] * bf2f(eo[(size_t)s * H_]);
  gl[tid] = g;
  __syncthreads();
  float y = 0.f;
  const float* w = Wd1 + tid * H_;
  for (int j = 0; j < H_; ++j) y += w[j] * gl[j];
  y = fmaxf(y, 0.f) * Wd2[tid];
  red[tid] = y;
  __syncthreads();
  for (int s = 128; s > 0; s >>= 1) {
    if (tid < s) red[tid] += red[tid + s];
    __syncthreads();
  }
  if (tid == 0) out[b] = red[0];
}

extern "C" void kernel_launch(void* const* d_in, const int* in_sizes, int n_in,
                              void* d_out, int out_size, void* d_ws, size_t ws_size,
                              hipStream_t stream) {
  (void)in_sizes; (void)n_in; (void)out_size; (void)ws_size;
  const float* inp    = (const float*)d_in[0];
  const float* W_emb  = (const float*)d_in[1];
  const float* dec_in = (const float*)d_in[2];
  const float* eWih   = (const float*)d_in[3];
  const float* eWhh   = (const float*)d_in[4];
  const float* ebih   = (const float*)d_in[5];
  const float* ebhh   = (const float*)d_in[6];
  const float* pWih   = (const float*)d_in[7];
  const float* pWhh   = (const float*)d_in[8];
  const float* pbih   = (const float*)d_in[9];
  const float* pbhh   = (const float*)d_in[10];
  const float* Wq     = (const float*)d_in[11];
  const float* bq     = (const float*)d_in[12];
  const float* Wref   = (const float*)d_in[13];
  const float* bref   = (const float*)d_in[14];
  const float* V      = (const float*)d_in[15];
  const float* Wd1    = (const float*)d_in[16];
  const float* Wd2    = (const float*)d_in[17];
  float* out = (float*)d_out;

  char* ws = (char*)d_ws;
  unsigned short* enc_out = (unsigned short*)(ws + OFF_ENC);
  unsigned short* WhhE    = (unsigned short*)(ws + OFF_WHHE);
  unsigned short* WhhP    = (unsigned short*)(ws + OFF_WHHP);
  unsigned short* Wrefb   = (unsigned short*)(ws + OFF_WREF);
  float* Menc  = (float*)(ws + OFF_MENC);
  float* biasE = (float*)(ws + OFF_BIASE);
  float* xpv   = (float*)(ws + OFF_XPV);
  unsigned int* flags = (unsigned int*)(ws + OFF_FLAGS);
  unsigned short* hx  = (unsigned short*)(ws + OFF_HX);
  float* hfin = (float*)(ws + OFF_HFIN);
  float* qbuf = (float*)(ws + OFF_QBUF);
  float* ubuf = (float*)(ws + OFF_UBUF);

  hipLaunchKernelGGL(k0_prep, dim3(256), dim3(256), 0, stream,
                     eWih, eWhh, ebih, ebhh, pWih, pWhh, pbih, pbhh, W_emb, dec_in,
                     Wref, WhhE, WhhP, Wrefb, Menc, biasE, xpv, flags, ubuf);
  hipLaunchKernelGGL(k1_lstm, dim3(32), dim3(512), 0, stream,
                     inp, WhhE, WhhP, Menc, biasE, xpv, enc_out, hx, flags, hfin);
  hipLaunchKernelGGL(k1b_q, dim3(256), dim3(256), 0, stream, hfin, Wq, bq, qbuf);
  hipLaunchKernelGGL(k2_att, dim3(2048), dim3(512), 0, stream,
                     enc_out, Wrefb, qbuf, bref, V, ubuf);
  hipLaunchKernelGGL(k3_head, dim3(256), dim3(256), 0, stream,
                     ubuf, enc_out, Wd1, Wd2, out);
}